// Round 7
// baseline (131.874 us; speedup 1.0000x reference)
//
#include <hip/hip_runtime.h>
#include <hip/hip_bf16.h>
#include <cstdint>

#define B_SIZE 4096
#define TWO_B  8192
#define DIM    512           // row length; fp8 => 512 bytes per row
#define NPAIRS 2080          // 64*65/2 upper-triangular tile pairs = 8 XCDs * 260
// exp(x/t) = exp2(x * log2(e)/t), t = 0.5
#define EXP_SCALE 2.8853900817779268f

typedef __attribute__((ext_vector_type(4))) float f32x4;

// raw waitcnt: vmcnt(n) with lgkmcnt/expcnt unconstrained (gfx9 encoding)
#define WAITVM(n) __builtin_amdgcn_s_waitcnt(0xF70 | (n))
#define BARRIER() __builtin_amdgcn_s_barrier()

// ---------- helpers ----------
__device__ __forceinline__ void async16(const void* g, void* l) {
    __builtin_amdgcn_global_load_lds(
        (const __attribute__((address_space(1))) unsigned int*)g,
        (__attribute__((address_space(3))) unsigned int*)l,
        16, 0, 0);
}

// ---------- kernel 1: L2-normalize rows -> fp8 reps, fp32 positives, zero denom/out ----------
// One wave per row-pair (emb_i[b], emb_j[b]); no LDS, no __syncthreads, butterfly shuffles.
// 256 blocks x 4 waves x 4 iterations = 4096 rows.
__global__ __launch_bounds__(256) void norm_pos_kernel(
    const float* __restrict__ emb_i, const float* __restrict__ emb_j,
    unsigned char* __restrict__ reps, float* __restrict__ pos,
    float* __restrict__ denom, float* __restrict__ out)
{
    int t = threadIdx.x, b0 = blockIdx.x;
    int lane = t & 63, w = t >> 6;
    int gz = b0 * 256 + t;
    if (gz < TWO_B) denom[gz] = 0.0f;          // zero-init, visible at kernel boundary
    if (b0 == 32 && t == 0) out[0] = 0.0f;     // loss kernel accumulates atomically

    #pragma unroll
    for (int it = 0; it < 4; it++) {
        int b = b0 * 4 + w + it * 1024;
        const float4* ri = (const float4*)(emb_i + (size_t)b * DIM);
        const float4* rj = (const float4*)(emb_j + (size_t)b * DIM);
        float4 xi0 = ri[lane * 2], xi1 = ri[lane * 2 + 1];
        float4 xj0 = rj[lane * 2], xj1 = rj[lane * 2 + 1];
        float si = xi0.x*xi0.x + xi0.y*xi0.y + xi0.z*xi0.z + xi0.w*xi0.w
                 + xi1.x*xi1.x + xi1.y*xi1.y + xi1.z*xi1.z + xi1.w*xi1.w;
        float sj = xj0.x*xj0.x + xj0.y*xj0.y + xj0.z*xj0.z + xj0.w*xj0.w
                 + xj1.x*xj1.x + xj1.y*xj1.y + xj1.z*xj1.z + xj1.w*xj1.w;
        #pragma unroll
        for (int o = 1; o < 64; o <<= 1) { si += __shfl_xor(si, o, 64); sj += __shfl_xor(sj, o, 64); }
        float rni = 1.0f / fmaxf(sqrtf(si), 1e-12f);
        float rnj = 1.0f / fmaxf(sqrtf(sj), 1e-12f);
        float4 zi0, zi1, zj0, zj1;
        zi0.x = xi0.x*rni; zi0.y = xi0.y*rni; zi0.z = xi0.z*rni; zi0.w = xi0.w*rni;
        zi1.x = xi1.x*rni; zi1.y = xi1.y*rni; zi1.z = xi1.z*rni; zi1.w = xi1.w*rni;
        zj0.x = xj0.x*rnj; zj0.y = xj0.y*rnj; zj0.z = xj0.z*rnj; zj0.w = xj0.w*rnj;
        zj1.x = xj1.x*rnj; zj1.y = xj1.y*rnj; zj1.z = xj1.z*rnj; zj1.w = xj1.w*rnj;
        // pack 8 floats -> 8 OCP e4m3 bytes per row per lane
        int a0 = __builtin_amdgcn_cvt_pk_fp8_f32(zi0.x, zi0.y, 0, false);
        a0     = __builtin_amdgcn_cvt_pk_fp8_f32(zi0.z, zi0.w, a0, true);
        int a1 = __builtin_amdgcn_cvt_pk_fp8_f32(zi1.x, zi1.y, 0, false);
        a1     = __builtin_amdgcn_cvt_pk_fp8_f32(zi1.z, zi1.w, a1, true);
        int b0p = __builtin_amdgcn_cvt_pk_fp8_f32(zj0.x, zj0.y, 0, false);
        b0p    = __builtin_amdgcn_cvt_pk_fp8_f32(zj0.z, zj0.w, b0p, true);
        int b1 = __builtin_amdgcn_cvt_pk_fp8_f32(zj1.x, zj1.y, 0, false);
        b1     = __builtin_amdgcn_cvt_pk_fp8_f32(zj1.z, zj1.w, b1, true);
        ((int2*)(reps + (size_t)b * DIM))[lane]            = make_int2(a0, a1);
        ((int2*)(reps + (size_t)(b + B_SIZE) * DIM))[lane] = make_int2(b0p, b1);
        float d = zi0.x*zj0.x + zi0.y*zj0.y + zi0.z*zj0.z + zi0.w*zj0.w
                + zi1.x*zj1.x + zi1.y*zj1.y + zi1.z*zj1.z + zi1.w*zj1.w;
        #pragma unroll
        for (int o = 1; o < 64; o <<= 1) d += __shfl_xor(d, o, 64);
        if (lane == 0) pos[b] = d;
    }
}

// ---------- kernel 2: symmetric fused R*R^T (fp8 MFMA) + masked exp row/col sums ----------
#define BM 128
#define BK 64
#define KITERS 8             // DIM / BK

__global__ __launch_bounds__(256) void sim_denom_kernel(
    const unsigned char* __restrict__ reps,
    const int* __restrict__ target,
    float* __restrict__ denom)
{
    __shared__ __align__(16) unsigned char As0[BM * BK];
    __shared__ __align__(16) unsigned char As1[BM * BK];
    __shared__ __align__(16) unsigned char Bs0[BM * BK];
    __shared__ __align__(16) unsigned char Bs1[BM * BK];

    int t = threadIdx.x;
    // --- XCD-aware remap: consecutive blockIdx round-robin over 8 XCDs, so give each
    // XCD a CONTIGUOUS 260-run of the locality-ordered supertile sequence (2080 = 8*260).
    int raw = blockIdx.x;
    int id = (raw & 7) * 260 + (raw >> 3);

    // --- supertile order: 4x4 supertiles of 16x16 tiles over the 64-tile triangle ---
    const int sI[10]  = {0,0,0,0,1,1,1,2,2,3};
    const int sJ[10]  = {0,1,2,3,1,2,3,2,3,3};
    const int off[11] = {0,136,392,648,904,1040,1296,1552,1688,1944,2080};
    int s = 0;
    while (off[s + 1] <= id) s++;
    int l = id - off[s];
    int u, v;
    if (sI[s] == sJ[s]) {                       // triangular 16x16: start(u)=u*(33-u)/2
        u = 0;
        while (((u + 1) * (32 - u)) / 2 <= l) u++;
        v = u + (l - (u * (33 - u)) / 2);
    } else { u = l >> 4; v = l & 15; }
    int bi = sI[s] * 16 + u;
    int bj = sJ[s] * 16 + v;
    int brow = bi * BM;
    int bcol = bj * BM;

    int wave = t >> 6, lane = t & 63;
    int wr = wave >> 1, wc = wave & 1;       // 2x2 waves, each 64x64 output
    int quad = lane >> 4, lm = lane & 15;

    f32x4 acc[4][4];
    #pragma unroll
    for (int i = 0; i < 4; i++)
        #pragma unroll
        for (int j = 0; j < 4; j++) acc[i][j] = (f32x4)0.0f;

    // staging: per call c (0..1): thread t -> row c*64 + (t>>2), LDS byte c*4096 + t*16,
    // swizzled source piece = (t&3) ^ ((row ^ (row>>2)) & 3)
    int srow = t >> 2;
    int sp   = (t & 3) ^ ((srow ^ (srow >> 2)) & 3);
    const unsigned char* gA = reps + (size_t)(brow + srow) * DIM + sp * 16;
    const unsigned char* gB = reps + (size_t)(bcol + srow) * DIM + sp * 16;

    auto stage = [&](unsigned char* Ab, unsigned char* Bb, int k0) {
        #pragma unroll
        for (int c = 0; c < 2; c++) {
            async16(gA + k0 + c * 64 * DIM, Ab + t * 16 + c * 4096);
            async16(gB + k0 + c * 64 * DIM, Bb + t * 16 + c * 4096);
        }
    };
    auto compute = [&](const unsigned char* Ab, const unsigned char* Bb) {
        #pragma unroll
        for (int ss = 0; ss < 2; ss++) {       // two K=32 sub-steps of BK=64
            long af[4], bf[4];
            #pragma unroll
            for (int mi = 0; mi < 4; mi++) {
                int rl = wr * 64 + mi * 16 + lm;
                int p = (ss * 2 + (quad >> 1)) ^ ((rl ^ (rl >> 2)) & 3);
                af[mi] = *(const long*)(Ab + rl * 64 + p * 16 + (quad & 1) * 8);
            }
            #pragma unroll
            for (int ni = 0; ni < 4; ni++) {
                int cl = wc * 64 + ni * 16 + lm;
                int p = (ss * 2 + (quad >> 1)) ^ ((cl ^ (cl >> 2)) & 3);
                bf[ni] = *(const long*)(Bb + cl * 64 + p * 16 + (quad & 1) * 8);
            }
            #pragma unroll
            for (int mi = 0; mi < 4; mi++)
                #pragma unroll
                for (int ni = 0; ni < 4; ni++)
                    acc[mi][ni] = __builtin_amdgcn_mfma_f32_16x16x32_fp8_fp8(
                        af[mi], bf[ni], acc[mi][ni], 0, 0, 0);
        }
    };

    // prologue: two tiles in flight (8 DMAs outstanding per wave)
    stage(As0, Bs0, 0);
    stage(As1, Bs1, BK);

    #pragma unroll
    for (int k = 0; k < KITERS; k++) {
        unsigned char* Ac = (k & 1) ? As1 : As0;
        unsigned char* Bc = (k & 1) ? Bs1 : Bs0;
        if (k < KITERS - 1) WAITVM(4); else WAITVM(0);   // drain loads(k), keep loads(k+1) in flight
        BARRIER();                         // all waves' loads(k) landed
        compute(Ac, Bc);
        BARRIER();                         // all waves done reading buf(k)
        if (k + 2 < KITERS) stage(Ac, Bc, (k + 2) * BK);
    }

    // epilogue: C/D layout col=lane&15, row=quad*4+reg; labels read direct (L2-hot)
    bool haspos = (bj - bi == 32);   // |rg-cg|==4096 only possible then (at rl==cl)
    int labc[4];
    #pragma unroll
    for (int ni = 0; ni < 4; ni++)
        labc[ni] = target[(bcol + wc * 64 + ni * 16 + lm) & (B_SIZE - 1)];

    float colacc[4] = {0.f, 0.f, 0.f, 0.f};
    #pragma unroll
    for (int mi = 0; mi < 4; mi++) {
        #pragma unroll
        for (int r = 0; r < 4; r++) {
            int rl = wr * 64 + mi * 16 + quad * 4 + r;
            int labr = target[(brow + rl) & (B_SIZE - 1)];
            float rowacc = 0.0f;
            #pragma unroll
            for (int ni = 0; ni < 4; ni++) {
                int cl = wc * 64 + ni * 16 + lm;
                bool pospair = haspos && (rl == cl);
                bool masked = (labr == labc[ni]) && !pospair;
                float e = masked ? 0.0f
                                 : __builtin_amdgcn_exp2f(acc[mi][ni][r] * EXP_SCALE);
                rowacc += e;
                colacc[ni] += e;
            }
            rowacc += __shfl_xor(rowacc, 1, 64);
            rowacc += __shfl_xor(rowacc, 2, 64);
            rowacc += __shfl_xor(rowacc, 4, 64);
            rowacc += __shfl_xor(rowacc, 8, 64);
            if (lm == 0) atomicAdd(&denom[brow + rl], rowacc);
        }
    }
    if (bi != bj) {
        #pragma unroll
        for (int ni = 0; ni < 4; ni++) {
            float c = colacc[ni];
            c += __shfl_xor(c, 16, 64);
            c += __shfl_xor(c, 32, 64);
            if (lane < 16) atomicAdd(&denom[bcol + wc * 64 + ni * 16 + lm], c);
        }
    }
}

// ---------- kernel 3: final loss (parallel, atomic accumulate into pre-zeroed out) ----------
__global__ __launch_bounds__(256) void loss_kernel(
    const float* __restrict__ denom, const float* __restrict__ pos,
    float* __restrict__ out)
{
    __shared__ float sc[4];
    int t = threadIdx.x, b = blockIdx.x;
    int i = b * 256 + t;
    float v = logf(denom[i] + 1e-7f);                  // 32 blocks x 256 = 8192
    float p = (i < B_SIZE) ? pos[i] : 0.0f;
    // loss = (sum log(denom) - (2/t) * sum pos) / 2B ; 2/t = 4
    float v2 = v - 4.0f * p;
    #pragma unroll
    for (int o = 32; o > 0; o >>= 1) v2 += __shfl_down(v2, o, 64);
    int lane = t & 63, w = t >> 6;
    if (lane == 0) sc[w] = v2;
    __syncthreads();
    if (t == 0) atomicAdd(out, (sc[0] + sc[1] + sc[2] + sc[3]) * (1.0f / (float)TWO_B));
}

// ---------- launcher ----------
extern "C" void kernel_launch(void* const* d_in, const int* in_sizes, int n_in,
                              void* d_out, int out_size, void* d_ws, size_t ws_size,
                              hipStream_t stream)
{
    const float* emb_i  = (const float*)d_in[0];
    const float* emb_j  = (const float*)d_in[1];
    const int*   target = (const int*)d_in[2];
    float* out = (float*)d_out;

    char* ws = (char*)d_ws;
    unsigned char* reps = (unsigned char*)ws;                        // 8192*512 = 4 MB (fp8)
    float* pos   = (float*)(ws + (size_t)TWO_B * DIM);               // 16 KB
    float* denom = (float*)(ws + (size_t)TWO_B * DIM + B_SIZE * 4);  // 32 KB

    norm_pos_kernel<<<256, 256, 0, stream>>>(emb_i, emb_j, reps, pos, denom, out);
    sim_denom_kernel<<<NPAIRS, 256, 0, stream>>>(reps, target, denom);
    loss_kernel<<<TWO_B / 256, 256, 0, stream>>>(denom, pos, out);
}